// Round 1
// baseline (1206.869 us; speedup 1.0000x reference)
//
#include <hip/hip_runtime.h>
#include <hip/hip_bf16.h>
#include <math.h>

// Problem constants
#define B_    64
#define T_    16
#define S_    1024
#define D_    2048
#define DFF_  2048
#define H_    8
#define DH_   256
#define L_    2
#define E_    32
#define HID_  64
#define GOUT_ 32
#define NN    (S_ * 9)

typedef unsigned short u16;
typedef float f32x4 __attribute__((ext_vector_type(4)));
typedef __bf16 bf16x8 __attribute__((ext_vector_type(8)));

__device__ __forceinline__ u16 f2bf_rne(float x) {
    union { float f; unsigned u; } c; c.f = x;
    unsigned u = c.u;
    unsigned r = (u + 0x7fffu + ((u >> 16) & 1u)) >> 16;
    return (u16)r;
}

// ---------------------------------------------------------------------------
// GEMM: C[M,N] = A[M,K] @ W[N,K]^T + bias[N]   (optional ReLU)
// A, W fp32 in HBM; converted to bf16 in registers during LDS staging;
// MFMA 16x16x32 bf16, fp32 accumulate. BM=BN=128, BK=32, 256 threads (4 waves),
// wave (wr,wc) owns a 64x64 quadrant as 4x4 fragments.
// LDS layout per operand: [mb 0..7][kslot 0..3][row 0..15][8 bf16]  (8 KiB)
// ---------------------------------------------------------------------------
template<int RELU>
__global__ __launch_bounds__(256)
void gemm_bt(const float* __restrict__ A, const float* __restrict__ W,
             const float* __restrict__ bias, float* __restrict__ C,
             int N, int K) {
    __shared__ __align__(16) u16 As[4096];
    __shared__ __align__(16) u16 Bs[4096];
    const int tid  = threadIdx.x;
    const int lane = tid & 63;
    const int wv   = tid >> 6;
    const int wr   = wv >> 1, wc = wv & 1;
    const long m0 = (long)blockIdx.y * 128;
    const long n0 = (long)blockIdx.x * 128;

    f32x4 acc[4][4];
#pragma unroll
    for (int i = 0; i < 4; i++)
#pragma unroll
        for (int j = 0; j < 4; j++)
#pragma unroll
            for (int r = 0; r < 4; r++) acc[i][j][r] = 0.0f;

    const int srow = tid >> 3;   // 0..31
    const int scol = tid & 7;    // float4 column within 32-wide k tile

    for (int kt = 0; kt < K; kt += 32) {
        __syncthreads();
#pragma unroll
        for (int p = 0; p < 4; p++) {
            const int row = p * 32 + srow;
            const int lidx = (row >> 4) * 512 + (scol >> 1) * 128 + (row & 15) * 8 + (scol & 1) * 4;
            const float4 va = *(const float4*)(A + (m0 + row) * (long)K + kt + scol * 4);
            *(ushort4*)&As[lidx] = make_ushort4(f2bf_rne(va.x), f2bf_rne(va.y),
                                                f2bf_rne(va.z), f2bf_rne(va.w));
            const float4 vb = *(const float4*)(W + (n0 + row) * (long)K + kt + scol * 4);
            *(ushort4*)&Bs[lidx] = make_ushort4(f2bf_rne(vb.x), f2bf_rne(vb.y),
                                                f2bf_rne(vb.z), f2bf_rne(vb.w));
        }
        __syncthreads();
        bf16x8 af[4], bfr[4];
#pragma unroll
        for (int i = 0; i < 4; i++) {
            const int fo = (lane >> 4) * 128 + (lane & 15) * 8;
            af[i]  = *(const bf16x8*)&As[(wr * 4 + i) * 512 + fo];
            bfr[i] = *(const bf16x8*)&Bs[(wc * 4 + i) * 512 + fo];
        }
#pragma unroll
        for (int i = 0; i < 4; i++)
#pragma unroll
            for (int j = 0; j < 4; j++)
                acc[i][j] = __builtin_amdgcn_mfma_f32_16x16x32_bf16(af[i], bfr[j], acc[i][j], 0, 0, 0);
    }

    // Epilogue. C/D layout: col = lane&15, row = (lane>>4)*4 + reg.
    const int crow = (lane >> 4) * 4;
    const int ccol = lane & 15;
#pragma unroll
    for (int i = 0; i < 4; i++) {
#pragma unroll
        for (int j = 0; j < 4; j++) {
            const long mb = m0 + wr * 64 + i * 16 + crow;
            const long nb = n0 + wc * 64 + j * 16 + ccol;
            const float bv = bias[nb];
#pragma unroll
            for (int r = 0; r < 4; r++) {
                float v = acc[i][j][r] + bv;
                if (RELU) v = fmaxf(v, 0.0f);
                C[(mb + r) * (long)N + nb] = v;
            }
        }
    }
}

// ---------------------------------------------------------------------------
// Heads: phase/loc/les logits (exact fp32) + argmax ids + les_act bits
// ---------------------------------------------------------------------------
__global__ __launch_bounds__(256)
void k_heads(const float* __restrict__ feat,
             const float* __restrict__ w_ph, const float* __restrict__ b_ph,
             const float* __restrict__ w_lc, const float* __restrict__ b_lc,
             const float* __restrict__ w_ls, const float* __restrict__ b_ls,
             float* __restrict__ o_ph, float* __restrict__ o_lc, float* __restrict__ o_ls,
             int* __restrict__ pid, int* __restrict__ lid, int* __restrict__ lesb) {
    const long s = blockIdx.x;
    const int tid = threadIdx.x;
    float a[17];
#pragma unroll
    for (int k = 0; k < 17; k++) a[k] = 0.0f;
    for (int d = tid; d < D_; d += 256) {
        const float f = feat[s * D_ + d];
        a[0] += f * w_ph[d * 3 + 0];
        a[1] += f * w_ph[d * 3 + 1];
        a[2] += f * w_ph[d * 3 + 2];
#pragma unroll
        for (int c = 0; c < 7; c++) a[3 + c]  += f * w_lc[d * 7 + c];
#pragma unroll
        for (int c = 0; c < 7; c++) a[10 + c] += f * w_ls[d * 7 + c];
    }
    __shared__ float red[4][17];
#pragma unroll
    for (int k = 0; k < 17; k++) {
        float v = a[k];
        for (int o = 32; o > 0; o >>= 1) v += __shfl_down(v, o, 64);
        if ((tid & 63) == 0) red[tid >> 6][k] = v;
    }
    __syncthreads();
    if (tid == 0) {
        float l[17];
#pragma unroll
        for (int k = 0; k < 17; k++) l[k] = red[0][k] + red[1][k] + red[2][k] + red[3][k];
        l[0] += b_ph[0]; l[1] += b_ph[1]; l[2] += b_ph[2];
#pragma unroll
        for (int c = 0; c < 7; c++) { l[3 + c] += b_lc[c]; l[10 + c] += b_ls[c]; }
        o_ph[s * 3 + 0] = l[0]; o_ph[s * 3 + 1] = l[1]; o_ph[s * 3 + 2] = l[2];
#pragma unroll
        for (int c = 0; c < 7; c++) { o_lc[s * 7 + c] = l[3 + c]; o_ls[s * 7 + c] = l[10 + c]; }
        int bp = 0;
        for (int j = 1; j < 3; j++) if (l[j] > l[bp]) bp = j;
        pid[s] = bp;
        int bl = 0;
        for (int c = 1; c < 7; c++) if (l[3 + c] > l[3 + bl]) bl = c;
        lid[s] = bl;
        int bits = 0;
        for (int c = 0; c < 7; c++) if (l[10 + c] > 0.0f) bits |= (1 << c);
        lesb[s] = bits;
    }
}

// ---------------------------------------------------------------------------
// Attention: per (b,h) block. T=16, Dh=256, mask on k-dim.
// ---------------------------------------------------------------------------
__global__ __launch_bounds__(256)
void k_attn(const float* __restrict__ qkv, const int* __restrict__ mask,
            float* __restrict__ ctx) {
    const int bh = blockIdx.x;
    const int b = bh >> 3, h = bh & 7;
    __shared__ float qs[16][257], ks[16][257], vs[16][257];
    __shared__ float sc[16][16];
    const int tid = threadIdx.x;
    for (int idx = tid; idx < 16 * 256; idx += 256) {
        const int t = idx >> 8, d = idx & 255;
        const long rb = ((long)(b * 16 + t)) * 6144 + h * 256 + d;
        qs[t][d] = qkv[rb];
        ks[t][d] = qkv[rb + 2048];
        vs[t][d] = qkv[rb + 4096];
    }
    __syncthreads();
    {
        const int i = tid >> 4, j = tid & 15;
        float dot = 0.0f;
        for (int d = 0; d < 256; d++) dot += qs[i][d] * ks[j][d];
        float sv = dot * (1.0f / 16.0f);
        if (mask[b * 16 + j] == 0) sv = -1000000000.0f;
        sc[i][j] = sv;
    }
    __syncthreads();
    if (tid < 16) {
        const int i = tid;
        float m = sc[i][0];
#pragma unroll
        for (int j = 1; j < 16; j++) m = fmaxf(m, sc[i][j]);
        float p[16], sum = 0.0f;
#pragma unroll
        for (int j = 0; j < 16; j++) { p[j] = expf(sc[i][j] - m); sum += p[j]; }
        const float inv = 1.0f / sum;
#pragma unroll
        for (int j = 0; j < 16; j++) sc[i][j] = p[j] * inv;
    }
    __syncthreads();
    {
        const int i = tid >> 4, c = tid & 15;
        float av[16];
#pragma unroll
        for (int j = 0; j < 16; j++) av[j] = sc[i][j];
#pragma unroll
        for (int o = 0; o < 16; o++) {
            const int d = o * 16 + c;
            float accv = 0.0f;
#pragma unroll
            for (int j = 0; j < 16; j++) accv += av[j] * vs[j][d];
            ctx[((long)(b * 16 + i)) * 2048 + h * 256 + d] = accv;
        }
    }
}

// ---------------------------------------------------------------------------
// LayerNorm over rows of 2048: out = LN(xprev + delta)*g + b  (two-pass)
// ---------------------------------------------------------------------------
__global__ __launch_bounds__(256)
void k_ln(const float* __restrict__ xprev, const float* __restrict__ delta,
          const float* __restrict__ g, const float* __restrict__ bt,
          float* __restrict__ out) {
    __shared__ float buf[D_];
    __shared__ float red[8];
    const long s = blockIdx.x;
    const int tid = threadIdx.x;
    float lsum = 0.0f;
    for (int d = tid; d < D_; d += 256) {
        const float v = xprev[s * D_ + d] + delta[s * D_ + d];
        buf[d] = v;
        lsum += v;
    }
    for (int o = 32; o > 0; o >>= 1) lsum += __shfl_down(lsum, o, 64);
    if ((tid & 63) == 0) red[tid >> 6] = lsum;
    __syncthreads();
    const float mean = (red[0] + red[1] + red[2] + red[3]) * (1.0f / D_);
    float lvar = 0.0f;
    for (int d = tid; d < D_; d += 256) { const float dv = buf[d] - mean; lvar += dv * dv; }
    for (int o = 32; o > 0; o >>= 1) lvar += __shfl_down(lvar, o, 64);
    if ((tid & 63) == 0) red[4 + (tid >> 6)] = lvar;
    __syncthreads();
    const float var = (red[4] + red[5] + red[6] + red[7]) * (1.0f / D_);
    const float rstd = 1.0f / sqrtf(var + 1e-5f);
    for (int d = tid; d < D_; d += 256)
        out[s * D_ + d] = (buf[d] - mean) * rstd * g[d] + bt[d];
}

// ---------------------------------------------------------------------------
// Token scores: scores[s] = x[s] . w_score + b_score
// ---------------------------------------------------------------------------
__global__ __launch_bounds__(256)
void k_scores(const float* __restrict__ x, const float* __restrict__ w,
              const float* __restrict__ bsc, float* __restrict__ scores) {
    const long s = blockIdx.x;
    const int tid = threadIdx.x;
    __shared__ float red[4];
    float a = 0.0f;
    for (int d = tid; d < D_; d += 256) a += x[s * D_ + d] * w[d];
    for (int o = 32; o > 0; o >>= 1) a += __shfl_down(a, o, 64);
    if ((tid & 63) == 0) red[tid >> 6] = a;
    __syncthreads();
    if (tid == 0) scores[s] = red[0] + red[1] + red[2] + red[3] + bsc[0];
}

// Softmax over T per batch + valid flags
__global__ void k_softT(const float* __restrict__ scores, const int* __restrict__ mask,
                        float* __restrict__ wts, int* __restrict__ validb) {
    const int b = blockIdx.x;
    const int t = threadIdx.x;  // blockDim 64, lanes 0..15 active
    float sv = -__builtin_inff();
    int mk = 0;
    if (t < 16) {
        mk = mask[b * 16 + t];
        sv = mk ? scores[b * 16 + t] : -__builtin_inff();
    }
    float m = sv;
    for (int o = 8; o > 0; o >>= 1) m = fmaxf(m, __shfl_xor(m, o, 16));
    float p = (t < 16) ? expf(sv - m) : 0.0f;
    float sum = p;
    for (int o = 8; o > 0; o >>= 1) sum += __shfl_xor(sum, o, 16);
    if (t < 16) {
        const float wv = p / sum;
        wts[b * 16 + t] = wv;
        validb[b * 16 + t] = (mk && (wv >= 0.05f)) ? 1 : 0;
    }
}

// pooled[b][d] = sum_t wts[b,t] * x[b,t,d]     grid (8, 64)
__global__ __launch_bounds__(256)
void k_pooled(const float* __restrict__ x, const float* __restrict__ wts,
              float* __restrict__ pooled) {
    const int b = blockIdx.y;
    const int d = blockIdx.x * 256 + threadIdx.x;
    float acc = 0.0f;
#pragma unroll
    for (int t = 0; t < 16; t++)
        acc += wts[b * 16 + t] * x[((long)(b * 16 + t)) * D_ + d];
    pooled[(long)b * D_ + d] = acc;
}

// next-valid chain (reverse scan) + prev + has_nxt. Single block.
__global__ __launch_bounds__(1024)
void k_nxt(const int* __restrict__ validb, int* __restrict__ nxt,
           int* __restrict__ prevb, int* __restrict__ hasn) {
    __shared__ int v[S_], nx[S_], pv[S_];
    const int t = threadIdx.x;
    v[t] = validb[t];
    pv[t] = -1;
    __syncthreads();
    if (t == 0) {
        int carry = -1;
        for (int i = S_ - 1; i >= 0; i--) { nx[i] = carry; if (v[i]) carry = i; }
    }
    __syncthreads();
    const int h = (v[t] && nx[t] >= 0) ? 1 : 0;
    if (h) pv[nx[t]] = t;   // injective among valid
    __syncthreads();
    nxt[t] = nx[t];
    hasn[t] = h;
    prevb[t] = pv[t];
}

// 9-node intra-sample adjacency: 0-1, 1-{2..8}, all pairs within {2..8}
__device__ __forceinline__ bool adj9(int u, int v) {
    if (u == v) return false;
    const int mn = u < v ? u : v;
    const int mx = u < v ? v : u;
    return !(mn == 0 && mx >= 2);
}

__global__ __launch_bounds__(64)
void k_deg(const int* __restrict__ validb, const int* __restrict__ lesb,
           const int* __restrict__ hasn, const int* __restrict__ prevb,
           float* __restrict__ deg, float* __restrict__ dinv) {
    const int s = blockIdx.x;
    const int t = threadIdx.x;
    __shared__ float nm[9];
    if (t < 9) {
        const int vl = validb[s];
        nm[t] = (t < 2) ? (vl ? 1.0f : 0.0f)
                        : ((vl && ((lesb[s] >> (t - 2)) & 1)) ? 1.0f : 0.0f);
    }
    __syncthreads();
    if (t < 9) {
        float dg = 1.0f;
        for (int u = 0; u < 9; u++)
            if (adj9(u, t)) dg += nm[u] * nm[t];
        if (t == 0) {
            dg += (float)hasn[s];
            if (prevb[s] >= 0) dg += 1.0f;
        }
        deg[s * 9 + t] = dg;
        dinv[s * 9 + t] = 1.0f / sqrtf(dg);
    }
}

// GCN layer-1 matmul: h1pre[N,64] = nodes[N,32] @ W1[32,64]  (embeddings inline)
__global__ __launch_bounds__(64)
void k_mm1(const int* __restrict__ pid, const int* __restrict__ lid,
           const float* __restrict__ embp, const float* __restrict__ embl,
           const float* __restrict__ lesw, const float* __restrict__ lesbv,
           const float* __restrict__ W1, float* __restrict__ h1pre) {
    const int s = blockIdx.x;
    const int t = threadIdx.x;
    __shared__ float nf[9][32];
    __shared__ float wl[32][64];
    for (int idx = t; idx < 9 * 32; idx += 64) {
        const int j = idx >> 5, e = idx & 31;
        float v;
        if (j == 0)      v = embp[pid[s] * 32 + e];
        else if (j == 1) v = embl[lid[s] * 32 + e];
        else             v = lesw[(j - 2) * 32 + e] + lesbv[e];
        nf[j][e] = v;
    }
    for (int idx = t; idx < 32 * 64; idx += 64) wl[idx >> 6][idx & 63] = W1[idx];
    __syncthreads();
    for (int j = 0; j < 9; j++) {
        float acc = 0.0f;
#pragma unroll
        for (int e = 0; e < 32; e++) acc += nf[j][e] * wl[e][t];
        h1pre[((long)(s * 9 + j)) * 64 + t] = acc;
    }
}

// GCN aggregate: out = relu(agg + h/deg + bias). blockDim = F.
template<int F>
__global__ void k_agg(const float* __restrict__ hpre, const float* __restrict__ deg,
                      const float* __restrict__ dinv, const int* __restrict__ validb,
                      const int* __restrict__ lesb, const int* __restrict__ hasn,
                      const int* __restrict__ prevb, const int* __restrict__ nxt,
                      const float* __restrict__ bias, float* __restrict__ out) {
    const int s = blockIdx.x;
    const int t = threadIdx.x;
    __shared__ float hp[11][F];
    __shared__ float nm[9], di[11], dgo[9];
    for (int idx = t; idx < 11 * F; idx += F) {
        const int nl = idx / F, f = idx % F;
        float v = 0.0f;
        if (nl < 9) v = hpre[((long)(s * 9 + nl)) * F + f];
        else if (nl == 9)  { const int nx = nxt[s];  if (nx >= 0) v = hpre[((long)(nx * 9)) * F + f]; }
        else               { const int pb = prevb[s]; if (pb >= 0) v = hpre[((long)(pb * 9)) * F + f]; }
        hp[nl][f] = v;
    }
    if (t < 9) {
        const int vl = validb[s];
        nm[t] = (t < 2) ? (vl ? 1.0f : 0.0f)
                        : ((vl && ((lesb[s] >> (t - 2)) & 1)) ? 1.0f : 0.0f);
        di[t] = dinv[s * 9 + t];
        dgo[t] = deg[s * 9 + t];
    }
    if (t == 0) {
        const int nx = nxt[s];
        di[9]  = (nx >= 0) ? dinv[nx * 9] : 0.0f;
        const int pb = prevb[s];
        di[10] = (pb >= 0) ? dinv[pb * 9] : 0.0f;
    }
    __syncthreads();
    const float wn = (float)hasn[s];
    const float wp = (prevb[s] >= 0) ? 1.0f : 0.0f;
    for (int j = 0; j < 9; j++) {
        float acc = hp[j][t] / dgo[j] + bias[t];
        const float djj = di[j], nmj = nm[j];
        for (int u = 0; u < 9; u++)
            if (adj9(u, j)) acc += di[u] * djj * nm[u] * nmj * hp[u][t];
        if (j == 0) {
            acc += di[9]  * djj * wn * hp[9][t];
            acc += di[10] * djj * wp * hp[10][t];
        }
        out[((long)(s * 9 + j)) * F + t] = fmaxf(acc, 0.0f);
    }
}

// GCN layer-2 matmul: h2pre[N,32] = h1[N,64] @ W2[64,32]
__global__ __launch_bounds__(64)
void k_mm2(const float* __restrict__ h1, const float* __restrict__ W2,
           float* __restrict__ h2pre) {
    const int s = blockIdx.x;
    const int t = threadIdx.x;
    __shared__ float hf[9][64];
    __shared__ float wl[64][32];
    for (int idx = t; idx < 9 * 64; idx += 64) hf[idx >> 6][idx & 63] = h1[(long)s * 9 * 64 + idx];
    for (int idx = t; idx < 64 * 32; idx += 64) wl[idx >> 5][idx & 31] = W2[idx];
    __syncthreads();
    const int o = t & 31, jh = t >> 5;
    for (int j = jh; j < 9; j += 2) {
        float acc = 0.0f;
#pragma unroll
        for (int e = 0; e < 64; e++) acc += hf[j][e] * wl[e][o];
        h2pre[((long)(s * 9 + j)) * 32 + o] = acc;
    }
}

// samp_mean + gnn_pooled fused. grid B, block 32 (thread = gout dim)
__global__ void k_sampgnn(const float* __restrict__ h2, const int* __restrict__ validb,
                          const int* __restrict__ lesb, float* __restrict__ gnnp) {
    const int b = blockIdx.x;
    const int t = threadIdx.x;
    float acc = 0.0f, vcnt = 0.0f;
    for (int tt = 0; tt < 16; tt++) {
        const int s = b * 16 + tt;
        if (validb[s]) {
            const int lb = lesb[s];
            float cnt = 2.0f;
            float sm = h2[((long)(s * 9 + 0)) * 32 + t] + h2[((long)(s * 9 + 1)) * 32 + t];
#pragma unroll
            for (int k = 0; k < 7; k++) {
                if ((lb >> k) & 1) { cnt += 1.0f; sm += h2[((long)(s * 9 + 2 + k)) * 32 + t]; }
            }
            acc += sm / fmaxf(cnt, 1.0f);
            vcnt += 1.0f;
        }
    }
    gnnp[b * 32 + t] = acc / fmaxf(vcnt, 1.0f);
}

// diag head: logits, conf, ent
__global__ __launch_bounds__(256)
void k_diag(const float* __restrict__ pooled, const float* __restrict__ gnnp,
            const float* __restrict__ wd, const float* __restrict__ bd,
            float* __restrict__ o_dg, float* __restrict__ o_cf, float* __restrict__ o_en) {
    const int b = blockIdx.x;
    const int tid = threadIdx.x;
    float a[7];
#pragma unroll
    for (int c = 0; c < 7; c++) a[c] = 0.0f;
    for (int d = tid; d < 2080; d += 256) {
        const float v = (d < 2048) ? pooled[(long)b * 2048 + d] : gnnp[b * 32 + (d - 2048)];
#pragma unroll
        for (int c = 0; c < 7; c++) a[c] += v * wd[d * 7 + c];
    }
    __shared__ float red[4][7];
#pragma unroll
    for (int c = 0; c < 7; c++) {
        float v = a[c];
        for (int o = 32; o > 0; o >>= 1) v += __shfl_down(v, o, 64);
        if ((tid & 63) == 0) red[tid >> 6][c] = v;
    }
    __syncthreads();
    if (tid == 0) {
        float l[7];
        float m = -__builtin_inff();
#pragma unroll
        for (int c = 0; c < 7; c++) {
            l[c] = red[0][c] + red[1][c] + red[2][c] + red[3][c] + bd[c];
            o_dg[b * 7 + c] = l[c];
            m = fmaxf(m, l[c]);
        }
        float p[7], sum = 0.0f;
#pragma unroll
        for (int c = 0; c < 7; c++) { p[c] = expf(l[c] - m); sum += p[c]; }
        const float inv = 1.0f / sum;
        float conf = 0.0f, ent = 0.0f;
#pragma unroll
        for (int c = 0; c < 7; c++) {
            const float pr = p[c] * inv;
            conf = fmaxf(conf, pr);
            ent -= pr * logf(pr + 1e-8f);
        }
        o_cf[b] = conf;
        o_en[b] = ent * (1.0f / 1.9459101090932196f);  // / log(7)
    }
}

// ---------------------------------------------------------------------------
extern "C" void kernel_launch(void* const* d_in, const int* in_sizes, int n_in,
                              void* d_out, int out_size, void* d_ws, size_t ws_size,
                              hipStream_t stream) {
    const float* feat      = (const float*)d_in[0];
    const float* w_phase   = (const float*)d_in[1];
    const float* b_phase   = (const float*)d_in[2];
    const float* w_loc     = (const float*)d_in[3];
    const float* b_loc     = (const float*)d_in[4];
    const float* w_les     = (const float*)d_in[5];
    const float* b_les     = (const float*)d_in[6];
    const float* emb_phase = (const float*)d_in[7];
    const float* emb_loc   = (const float*)d_in[8];
    const float* les_emb_w = (const float*)d_in[9];
    const float* les_emb_b = (const float*)d_in[10];
    const float* qkv_w     = (const float*)d_in[11];
    const float* qkv_b     = (const float*)d_in[12];
    const float* o_w       = (const float*)d_in[13];
    const float* o_b       = (const float*)d_in[14];
    const float* ln1_g     = (const float*)d_in[15];
    const float* ln1_b     = (const float*)d_in[16];
    const float* ln2_g     = (const float*)d_in[17];
    const float* ln2_b     = (const float*)d_in[18];
    const float* ff1_w     = (const float*)d_in[19];
    const float* ff1_b     = (const float*)d_in[20];
    const float* ff2_w     = (const float*)d_in[21];
    const float* ff2_b     = (const float*)d_in[22];
    const float* w_score   = (const float*)d_in[23];
    const float* b_score   = (const float*)d_in[24];
    const float* gcn1_w    = (const float*)d_in[25];
    const float* gcn1_b    = (const float*)d_in[26];
    const float* gcn2_w    = (const float*)d_in[27];
    const float* gcn2_b    = (const float*)d_in[28];
    const float* w_diag    = (const float*)d_in[29];
    const float* b_diag    = (const float*)d_in[30];
    const int*   mask      = (const int*)d_in[31];

    float* out  = (float*)d_out;
    float* o_ph = out;           // (S,3)
    float* o_lc = out + 3072;    // (S,7)
    float* o_ls = out + 10240;   // (S,7)
    float* o_dg = out + 17408;   // (B,7)
    float* o_cf = out + 17856;   // (B,)
    float* o_en = out + 17920;   // (B,)

    float* w = (float*)d_ws;
    float* x      = w; w += (long)S_ * D_;
    float* qkvb   = w; w += (long)S_ * 3 * D_;
    float* ctx    = w; w += (long)S_ * D_;
    float* tmp    = w; w += (long)S_ * D_;
    float* ffb    = w; w += (long)S_ * DFF_;
    float* scores = w; w += S_;
    float* wts    = w; w += S_;
    float* pooled = w; w += (long)B_ * D_;
    float* h1pre  = w; w += (long)NN * HID_;
    float* h1     = w; w += (long)NN * HID_;
    float* h2pre  = w; w += (long)NN * GOUT_;
    float* h2     = w; w += (long)NN * GOUT_;
    float* degv   = w; w += NN;
    float* dinvv  = w; w += NN;
    float* gnnp   = w; w += B_ * GOUT_;
    int* ivs    = (int*)w;
    int* pid    = ivs;
    int* lid    = ivs + S_;
    int* lesb   = ivs + 2 * S_;
    int* validb = ivs + 3 * S_;
    int* nxtb   = ivs + 4 * S_;
    int* prevb  = ivs + 5 * S_;
    int* hasn   = ivs + 6 * S_;

    k_heads<<<S_, 256, 0, stream>>>(feat, w_phase, b_phase, w_loc, b_loc, w_les, b_les,
                                    o_ph, o_lc, o_ls, pid, lid, lesb);

    const float* xin = feat;
    for (int l = 0; l < L_; l++) {
        gemm_bt<0><<<dim3(6144 / 128, 1024 / 128), 256, 0, stream>>>(
            xin, qkv_w + (long)l * 3 * D_ * D_, qkv_b + (long)l * 3 * D_, qkvb, 3 * D_, D_);
        k_attn<<<B_ * H_, 256, 0, stream>>>(qkvb, mask, ctx);
        gemm_bt<0><<<dim3(2048 / 128, 1024 / 128), 256, 0, stream>>>(
            ctx, o_w + (long)l * D_ * D_, o_b + (long)l * D_, tmp, D_, D_);
        k_ln<<<S_, 256, 0, stream>>>(xin, tmp, ln1_g + (long)l * D_, ln1_b + (long)l * D_, x);
        gemm_bt<1><<<dim3(2048 / 128, 1024 / 128), 256, 0, stream>>>(
            x, ff1_w + (long)l * DFF_ * D_, ff1_b + (long)l * DFF_, ffb, DFF_, D_);
        gemm_bt<0><<<dim3(2048 / 128, 1024 / 128), 256, 0, stream>>>(
            ffb, ff2_w + (long)l * D_ * DFF_, ff2_b + (long)l * D_, tmp, D_, DFF_);
        k_ln<<<S_, 256, 0, stream>>>(x, tmp, ln2_g + (long)l * D_, ln2_b + (long)l * D_, x);
        xin = x;
    }

    k_scores<<<S_, 256, 0, stream>>>(x, w_score, b_score, scores);
    k_softT<<<B_, 64, 0, stream>>>(scores, mask, wts, validb);
    k_pooled<<<dim3(8, B_), 256, 0, stream>>>(x, wts, pooled);
    k_nxt<<<1, 1024, 0, stream>>>(validb, nxtb, prevb, hasn);
    k_deg<<<S_, 64, 0, stream>>>(validb, lesb, hasn, prevb, degv, dinvv);
    k_mm1<<<S_, 64, 0, stream>>>(pid, lid, emb_phase, emb_loc, les_emb_w, les_emb_b, gcn1_w, h1pre);
    k_agg<64><<<S_, 64, 0, stream>>>(h1pre, degv, dinvv, validb, lesb, hasn, prevb, nxtb, gcn1_b, h1);
    k_mm2<<<S_, 64, 0, stream>>>(h1, gcn2_w, h2pre);
    k_agg<32><<<S_, 32, 0, stream>>>(h2pre, degv, dinvv, validb, lesb, hasn, prevb, nxtb, gcn2_b, h2);
    k_sampgnn<<<B_, 32, 0, stream>>>(h2, validb, lesb, gnnp);
    k_diag<<<B_, 256, 0, stream>>>(pooled, gnnp, w_diag, b_diag, o_dg, o_cf, o_en);
}

// Round 3
// 675.856 us; speedup vs baseline: 1.7857x; 1.7857x over previous
//
#include <hip/hip_runtime.h>
#include <hip/hip_bf16.h>
#include <math.h>

// Problem constants
#define B_    64
#define T_    16
#define S_    1024
#define D_    2048
#define DFF_  2048
#define H_    8
#define DH_   256
#define L_    2
#define E_    32
#define HID_  64
#define GOUT_ 32
#define NN    (S_ * 9)

typedef unsigned short u16;
typedef float f32x4 __attribute__((ext_vector_type(4)));
typedef __bf16 bf16x8 __attribute__((ext_vector_type(8)));

__device__ __forceinline__ u16 f2bf_rne(float x) {
    union { float f; unsigned u; } c; c.f = x;
    unsigned u = c.u;
    unsigned r = (u + 0x7fffu + ((u >> 16) & 1u)) >> 16;
    return (u16)r;
}

__device__ __forceinline__ void gll16(const u16* g, u16* l) {
    __builtin_amdgcn_global_load_lds(
        (const __attribute__((address_space(1))) unsigned int*)g,
        (__attribute__((address_space(3))) unsigned int*)l,
        16, 0, 0);
}

// ---------------------------------------------------------------------------
// fp32 -> bf16 bulk convert (memory-bound, vectorized 8/thread)
// ---------------------------------------------------------------------------
__global__ __launch_bounds__(256)
void k_f2b(const float* __restrict__ in, u16* __restrict__ out, long n) {
    const long stride = (long)gridDim.x * 256 * 8;
    for (long i = ((long)blockIdx.x * 256 + threadIdx.x) * 8; i < n; i += stride) {
        const float4 a = *(const float4*)(in + i);
        const float4 b = *(const float4*)(in + i + 4);
        *(ushort4*)(out + i)     = make_ushort4(f2bf_rne(a.x), f2bf_rne(a.y),
                                                f2bf_rne(a.z), f2bf_rne(a.w));
        *(ushort4*)(out + i + 4) = make_ushort4(f2bf_rne(b.x), f2bf_rne(b.y),
                                                f2bf_rne(b.z), f2bf_rne(b.w));
    }
}

// ---------------------------------------------------------------------------
// GEMM: C[M,N] = A[M,K] @ W[N,K]^T   (A, W bf16; fp32 accumulate)
// BM=BN=128, BK=32, 256 threads (4 waves), wave quadrant 64x64 (4x4 frags).
// global_load_lds width=16 staging into linear LDS [128 rows][32 bf16];
// double-buffered: prefetch tile t+1 while computing tile t (2-phase).
// EPI 0: C = acc + bias (fp32, full K).  EPI 1: partial per blockIdx.z.
// ---------------------------------------------------------------------------
template<int EPI>
__global__ __launch_bounds__(256)
void gemm_bf(const u16* __restrict__ A, const u16* __restrict__ W,
             const float* __restrict__ bias, float* __restrict__ C,
             int N, int K, int KS) {
    __shared__ __align__(16) u16 As0[128 * 32];
    __shared__ __align__(16) u16 Bs0[128 * 32];
    __shared__ __align__(16) u16 As1[128 * 32];
    __shared__ __align__(16) u16 Bs1[128 * 32];
    const int tid  = threadIdx.x;
    const int lane = tid & 63;
    const int wv   = tid >> 6;
    const int wr   = wv >> 1, wc = wv & 1;
    const long m0 = (long)blockIdx.y * 128;
    const long n0 = (long)blockIdx.x * 128;
    const int kbase = blockIdx.z * KS;

    f32x4 acc[4][4];
#pragma unroll
    for (int i = 0; i < 4; i++)
#pragma unroll
        for (int j = 0; j < 4; j++)
#pragma unroll
            for (int r = 0; r < 4; r++) acc[i][j][r] = 0.0f;

    // staging: wave wv owns chunks c0,c1 (16 rows each) of both operands.
    // chunk c, lane l -> row c*16 + l/4, k-offset (l&3)*8 (16B per lane).
    const int c0 = wv * 2, c1 = wv * 2 + 1;
    const int rsub = lane >> 2;
    const int kcol = (lane & 3) * 8;
    const u16* ga0 = A + (m0 + c0 * 16 + rsub) * (long)K + kbase + kcol;
    const u16* ga1 = A + (m0 + c1 * 16 + rsub) * (long)K + kbase + kcol;
    const u16* gb0 = W + (n0 + c0 * 16 + rsub) * (long)K + kbase + kcol;
    const u16* gb1 = W + (n0 + c1 * 16 + rsub) * (long)K + kbase + kcol;

    auto STAGE = [&](u16* dstA, u16* dstB) {
        gll16(ga0, dstA + c0 * 512);
        gll16(ga1, dstA + c1 * 512);
        gll16(gb0, dstB + c0 * 512);
        gll16(gb1, dstB + c1 * 512);
        ga0 += 32; ga1 += 32; gb0 += 32; gb1 += 32;
    };

    STAGE(As0, Bs0);
    __syncthreads();   // drains vmcnt -> tile 0 resident

    u16 *rA = As0, *rB = Bs0, *sA = As1, *sB = Bs1;
    const int nt = KS / 32;
    const int rbase = lane & 15;
    const int koff  = (lane >> 4) * 8;

    for (int t = 0; t < nt; ++t) {
        if (t + 1 < nt) STAGE(sA, sB);   // in flight during compute
        bf16x8 af[4], bfr[4];
#pragma unroll
        for (int i = 0; i < 4; i++) {
            af[i]  = *(const bf16x8*)&rA[(wr * 64 + i * 16 + rbase) * 32 + koff];
            bfr[i] = *(const bf16x8*)&rB[(wc * 64 + i * 16 + rbase) * 32 + koff];
        }
#pragma unroll
        for (int i = 0; i < 4; i++)
#pragma unroll
            for (int j = 0; j < 4; j++)
                acc[i][j] = __builtin_amdgcn_mfma_f32_16x16x32_bf16(af[i], bfr[j], acc[i][j], 0, 0, 0);
        __syncthreads();                 // next tile ready; reads of rA/rB done
        u16* t1 = rA; rA = sA; sA = t1;
        u16* t2 = rB; rB = sB; sB = t2;
    }

    // Epilogue. C/D layout: col = lane&15, row = (lane>>4)*4 + reg.
    float* Cout = (EPI == 1) ? (C + (long)blockIdx.z * ((long)S_ * N)) : C;
    const int crow = (lane >> 4) * 4;
    const int ccol = lane & 15;
#pragma unroll
    for (int i = 0; i < 4; i++) {
#pragma unroll
        for (int j = 0; j < 4; j++) {
            const long mb = m0 + wr * 64 + i * 16 + crow;
            const long nb = n0 + wc * 64 + j * 16 + ccol;
            float bv = 0.0f;
            if (EPI == 0) bv = bias[nb];
#pragma unroll
            for (int r = 0; r < 4; r++)
                Cout[(mb + r) * (long)N + nb] = acc[i][j][r] + bv;
        }
    }
}

// ---------------------------------------------------------------------------
// Heads: phase/loc/les logits (exact fp32) + argmax ids + les_act bits
// ---------------------------------------------------------------------------
__global__ __launch_bounds__(256)
void k_heads(const float* __restrict__ feat,
             const float* __restrict__ w_ph, const float* __restrict__ b_ph,
             const float* __restrict__ w_lc, const float* __restrict__ b_lc,
             const float* __restrict__ w_ls, const float* __restrict__ b_ls,
             float* __restrict__ o_ph, float* __restrict__ o_lc, float* __restrict__ o_ls,
             int* __restrict__ pid, int* __restrict__ lid, int* __restrict__ lesb) {
    const long s = blockIdx.x;
    const int tid = threadIdx.x;
    float a[17];
#pragma unroll
    for (int k = 0; k < 17; k++) a[k] = 0.0f;
    for (int d = tid; d < D_; d += 256) {
        const float f = feat[s * D_ + d];
        a[0] += f * w_ph[d * 3 + 0];
        a[1] += f * w_ph[d * 3 + 1];
        a[2] += f * w_ph[d * 3 + 2];
#pragma unroll
        for (int c = 0; c < 7; c++) a[3 + c]  += f * w_lc[d * 7 + c];
#pragma unroll
        for (int c = 0; c < 7; c++) a[10 + c] += f * w_ls[d * 7 + c];
    }
    __shared__ float red[4][17];
#pragma unroll
    for (int k = 0; k < 17; k++) {
        float v = a[k];
        for (int o = 32; o > 0; o >>= 1) v += __shfl_down(v, o, 64);
        if ((tid & 63) == 0) red[tid >> 6][k] = v;
    }
    __syncthreads();
    if (tid == 0) {
        float l[17];
#pragma unroll
        for (int k = 0; k < 17; k++) l[k] = red[0][k] + red[1][k] + red[2][k] + red[3][k];
        l[0] += b_ph[0]; l[1] += b_ph[1]; l[2] += b_ph[2];
#pragma unroll
        for (int c = 0; c < 7; c++) { l[3 + c] += b_lc[c]; l[10 + c] += b_ls[c]; }
        o_ph[s * 3 + 0] = l[0]; o_ph[s * 3 + 1] = l[1]; o_ph[s * 3 + 2] = l[2];
#pragma unroll
        for (int c = 0; c < 7; c++) { o_lc[s * 7 + c] = l[3 + c]; o_ls[s * 7 + c] = l[10 + c]; }
        int bp = 0;
        for (int j = 1; j < 3; j++) if (l[j] > l[bp]) bp = j;
        pid[s] = bp;
        int bl = 0;
        for (int c = 1; c < 7; c++) if (l[3 + c] > l[3 + bl]) bl = c;
        lid[s] = bl;
        int bits = 0;
        for (int c = 0; c < 7; c++) if (l[10 + c] > 0.0f) bits |= (1 << c);
        lesb[s] = bits;
    }
}

// ---------------------------------------------------------------------------
// Attention: per (b,h) block. T=16, Dh=256. Writes ctx as bf16 (feeds GEMM A).
// ---------------------------------------------------------------------------
__global__ __launch_bounds__(256)
void k_attn(const float* __restrict__ qkv, const int* __restrict__ mask,
            u16* __restrict__ ctxb) {
    const int bh = blockIdx.x;
    const int b = bh >> 3, h = bh & 7;
    __shared__ float qs[16][257], ks[16][257], vs[16][257];
    __shared__ float sc[16][16];
    const int tid = threadIdx.x;
    for (int idx = tid; idx < 16 * 256; idx += 256) {
        const int t = idx >> 8, d = idx & 255;
        const long rb = ((long)(b * 16 + t)) * 6144 + h * 256 + d;
        qs[t][d] = qkv[rb];
        ks[t][d] = qkv[rb + 2048];
        vs[t][d] = qkv[rb + 4096];
    }
    __syncthreads();
    {
        const int i = tid >> 4, j = tid & 15;
        float dot = 0.0f;
        for (int d = 0; d < 256; d++) dot += qs[i][d] * ks[j][d];
        float sv = dot * (1.0f / 16.0f);
        if (mask[b * 16 + j] == 0) sv = -1000000000.0f;
        sc[i][j] = sv;
    }
    __syncthreads();
    if (tid < 16) {
        const int i = tid;
        float m = sc[i][0];
#pragma unroll
        for (int j = 1; j < 16; j++) m = fmaxf(m, sc[i][j]);
        float p[16], sum = 0.0f;
#pragma unroll
        for (int j = 0; j < 16; j++) { p[j] = expf(sc[i][j] - m); sum += p[j]; }
        const float inv = 1.0f / sum;
#pragma unroll
        for (int j = 0; j < 16; j++) sc[i][j] = p[j] * inv;
    }
    __syncthreads();
    {
        const int i = tid >> 4, c = tid & 15;
        float av[16];
#pragma unroll
        for (int j = 0; j < 16; j++) av[j] = sc[i][j];
#pragma unroll
        for (int o = 0; o < 16; o++) {
            const int d = o * 16 + c;
            float accv = 0.0f;
#pragma unroll
            for (int j = 0; j < 16; j++) accv += av[j] * vs[j][d];
            ctxb[((long)(b * 16 + i)) * 2048 + h * 256 + d] = f2bf_rne(accv);
        }
    }
}

// ---------------------------------------------------------------------------
// LayerNorm fused with split-K combine:
// out = LN(xprev + sum_z part[z] + pb) * g + b  -> fp32 AND bf16 outputs
// ---------------------------------------------------------------------------
__global__ __launch_bounds__(256)
void k_ln4(const float* __restrict__ xprev, const float* __restrict__ part,
           const float* __restrict__ pb, const float* __restrict__ g,
           const float* __restrict__ bt, float* __restrict__ outf,
           u16* __restrict__ outb) {
    __shared__ float buf[D_];
    __shared__ float red[8];
    const long s = blockIdx.x;
    const int tid = threadIdx.x;
    const long base = s * D_;
    const long P = (long)S_ * D_;
    float lsum = 0.0f;
    for (int d = tid; d < D_; d += 256) {
        const long i = base + d;
        const float v = xprev[i] + pb[d]
                      + part[i] + part[i + P] + part[i + 2 * P] + part[i + 3 * P];
        buf[d] = v;
        lsum += v;
    }
    for (int o = 32; o > 0; o >>= 1) lsum += __shfl_down(lsum, o, 64);
    if ((tid & 63) == 0) red[tid >> 6] = lsum;
    __syncthreads();
    const float mean = (red[0] + red[1] + red[2] + red[3]) * (1.0f / D_);
    float lvar = 0.0f;
    for (int d = tid; d < D_; d += 256) { const float dv = buf[d] - mean; lvar += dv * dv; }
    for (int o = 32; o > 0; o >>= 1) lvar += __shfl_down(lvar, o, 64);
    if ((tid & 63) == 0) red[4 + (tid >> 6)] = lvar;
    __syncthreads();
    const float var = (red[4] + red[5] + red[6] + red[7]) * (1.0f / D_);
    const float rstd = 1.0f / sqrtf(var + 1e-5f);
    for (int d = tid; d < D_; d += 256) {
        const float v = (buf[d] - mean) * rstd * g[d] + bt[d];
        outf[base + d] = v;
        outb[base + d] = f2bf_rne(v);
    }
}

// split-K combine + bias + ReLU -> bf16 (for ff1 output)
__global__ __launch_bounds__(256)
void k_comb_relu(const float* __restrict__ part, const float* __restrict__ bias,
                 u16* __restrict__ outb) {
    const long i = ((long)blockIdx.x * 256 + threadIdx.x) * 4;  // over S_*DFF_
    const long P = (long)S_ * DFF_;
    const int n = (int)(i & (DFF_ - 1));
    float4 v  = *(const float4*)(part + i);
    const float4 v1 = *(const float4*)(part + i + P);
    const float4 v2 = *(const float4*)(part + i + 2 * P);
    const float4 v3 = *(const float4*)(part + i + 3 * P);
    const float4 bv = *(const float4*)(bias + n);
    v.x = fmaxf(v.x + v1.x + v2.x + v3.x + bv.x, 0.0f);
    v.y = fmaxf(v.y + v1.y + v2.y + v3.y + bv.y, 0.0f);
    v.z = fmaxf(v.z + v1.z + v2.z + v3.z + bv.z, 0.0f);
    v.w = fmaxf(v.w + v1.w + v2.w + v3.w + bv.w, 0.0f);
    *(ushort4*)(outb + i) = make_ushort4(f2bf_rne(v.x), f2bf_rne(v.y),
                                         f2bf_rne(v.z), f2bf_rne(v.w));
}

// ---------------------------------------------------------------------------
// Token scores: scores[s] = x[s] . w_score + b_score
// ---------------------------------------------------------------------------
__global__ __launch_bounds__(256)
void k_scores(const float* __restrict__ x, const float* __restrict__ w,
              const float* __restrict__ bsc, float* __restrict__ scores) {
    const long s = blockIdx.x;
    const int tid = threadIdx.x;
    __shared__ float red[4];
    float a = 0.0f;
    for (int d = tid; d < D_; d += 256) a += x[s * D_ + d] * w[d];
    for (int o = 32; o > 0; o >>= 1) a += __shfl_down(a, o, 64);
    if ((tid & 63) == 0) red[tid >> 6] = a;
    __syncthreads();
    if (tid == 0) scores[s] = red[0] + red[1] + red[2] + red[3] + bsc[0];
}

// Softmax over T per batch + valid flags
__global__ void k_softT(const float* __restrict__ scores, const int* __restrict__ mask,
                        float* __restrict__ wts, int* __restrict__ validb) {
    const int b = blockIdx.x;
    const int t = threadIdx.x;  // blockDim 64, lanes 0..15 active
    float sv = -__builtin_inff();
    int mk = 0;
    if (t < 16) {
        mk = mask[b * 16 + t];
        sv = mk ? scores[b * 16 + t] : -__builtin_inff();
    }
    float m = sv;
    for (int o = 8; o > 0; o >>= 1) m = fmaxf(m, __shfl_xor(m, o, 16));
    float p = (t < 16) ? expf(sv - m) : 0.0f;
    float sum = p;
    for (int o = 8; o > 0; o >>= 1) sum += __shfl_xor(sum, o, 16);
    if (t < 16) {
        const float wv = p / sum;
        wts[b * 16 + t] = wv;
        validb[b * 16 + t] = (mk && (wv >= 0.05f)) ? 1 : 0;
    }
}

// pooled[b][d] = sum_t wts[b,t] * x[b,t,d]     grid (8, 64)
__global__ __launch_bounds__(256)
void k_pooled(const float* __restrict__ x, const float* __restrict__ wts,
              float* __restrict__ pooled) {
    const int b = blockIdx.y;
    const int d = blockIdx.x * 256 + threadIdx.x;
    float acc = 0.0f;
#pragma unroll
    for (int t = 0; t < 16; t++)
        acc += wts[b * 16 + t] * x[((long)(b * 16 + t)) * D_ + d];
    pooled[(long)b * D_ + d] = acc;
}

// next-valid chain (reverse scan) + prev + has_nxt. Single block.
__global__ __launch_bounds__(1024)
void k_nxt(const int* __restrict__ validb, int* __restrict__ nxt,
           int* __restrict__ prevb, int* __restrict__ hasn) {
    __shared__ int v[S_], nx[S_], pv[S_];
    const int t = threadIdx.x;
    v[t] = validb[t];
    pv[t] = -1;
    __syncthreads();
    if (t == 0) {
        int carry = -1;
        for (int i = S_ - 1; i >= 0; i--) { nx[i] = carry; if (v[i]) carry = i; }
    }
    __syncthreads();
    const int h = (v[t] && nx[t] >= 0) ? 1 : 0;
    if (h) pv[nx[t]] = t;   // injective among valid
    __syncthreads();
    nxt[t] = nx[t];
    hasn[t] = h;
    prevb[t] = pv[t];
}

// 9-node intra-sample adjacency: 0-1, 1-{2..8}, all pairs within {2..8}
__device__ __forceinline__ bool adj9(int u, int v) {
    if (u == v) return false;
    const int mn = u < v ? u : v;
    const int mx = u < v ? v : u;
    return !(mn == 0 && mx >= 2);
}

__global__ __launch_bounds__(64)
void k_deg(const int* __restrict__ validb, const int* __restrict__ lesb,
           const int* __restrict__ hasn, const int* __restrict__ prevb,
           float* __restrict__ deg, float* __restrict__ dinv) {
    const int s = blockIdx.x;
    const int t = threadIdx.x;
    __shared__ float nm[9];
    if (t < 9) {
        const int vl = validb[s];
        nm[t] = (t < 2) ? (vl ? 1.0f : 0.0f)
                        : ((vl && ((lesb[s] >> (t - 2)) & 1)) ? 1.0f : 0.0f);
    }
    __syncthreads();
    if (t < 9) {
        float dg = 1.0f;
        for (int u = 0; u < 9; u++)
            if (adj9(u, t)) dg += nm[u] * nm[t];
        if (t == 0) {
            dg += (float)hasn[s];
            if (prevb[s] >= 0) dg += 1.0f;
        }
        deg[s * 9 + t] = dg;
        dinv[s * 9 + t] = 1.0f / sqrtf(dg);
    }
}

// GCN layer-1 matmul: h1pre[N,64] = nodes[N,32] @ W1[32,64]  (embeddings inline)
__global__ __launch_bounds__(64)
void k_mm1(const int* __restrict__ pid, const int* __restrict__ lid,
           const float* __restrict__ embp, const float* __restrict__ embl,
           const float* __restrict__ lesw, const float* __restrict__ lesbv,
           const float* __restrict__ W1, float* __restrict__ h1pre) {
    const int s = blockIdx.x;
    const int t = threadIdx.x;
    __shared__ float nf[9][32];
    __shared__ float wl[32][64];
    for (int idx = t; idx < 9 * 32; idx += 64) {
        const int j = idx >> 5, e = idx & 31;
        float v;
        if (j == 0)      v = embp[pid[s] * 32 + e];
        else if (j == 1) v = embl[lid[s] * 32 + e];
        else             v = lesw[(j - 2) * 32 + e] + lesbv[e];
        nf[j][e] = v;
    }
    for (int idx = t; idx < 32 * 64; idx += 64) wl[idx >> 6][idx & 63] = W1[idx];
    __syncthreads();
    for (int j = 0; j < 9; j++) {
        float acc = 0.0f;
#pragma unroll
        for (int e = 0; e < 32; e++) acc += nf[j][e] * wl[e][t];
        h1pre[((long)(s * 9 + j)) * 64 + t] = acc;
    }
}

// GCN aggregate: out = relu(agg + h/deg + bias). blockDim = F.
template<int F>
__global__ void k_agg(const float* __restrict__ hpre, const float* __restrict__ deg,
                      const float* __restrict__ dinv, const int* __restrict__ validb,
                      const int* __restrict__ lesb, const int* __restrict__ hasn,
                      const int* __restrict__ prevb, const int* __restrict__ nxt,
                      const float* __restrict__ bias, float* __restrict__ out) {
    const int s = blockIdx.x;
    const int t = threadIdx.x;
    __shared__ float hp[11][F];
    __shared__ float nm[9], di[11], dgo[9];
    for (int idx = t; idx < 11 * F; idx += F) {
        const int nl = idx / F, f = idx % F;
        float v = 0.0f;
        if (nl < 9) v = hpre[((long)(s * 9 + nl)) * F + f];
        else if (nl == 9)  { const int nx = nxt[s];  if (nx >= 0) v = hpre[((long)(nx * 9)) * F + f]; }
        else               { const int pb = prevb[s]; if (pb >= 0) v = hpre[((long)(pb * 9)) * F + f]; }
        hp[nl][f] = v;
    }
    if (t < 9) {
        const int vl = validb[s];
        nm[t] = (t < 2) ? (vl ? 1.0f : 0.0f)
                        : ((vl && ((lesb[s] >> (t - 2)) & 1)) ? 1.0f : 0.0f);
        di[t] = dinv[s * 9 + t];
        dgo[t] = deg[s * 9 + t];
    }
    if (t == 0) {
        const int nx = nxt[s];
        di[9]  = (nx >= 0) ? dinv[nx * 9] : 0.0f;
        const int pb = prevb[s];
        di[10] = (pb >= 0) ? dinv[pb * 9] : 0.0f;
    }
    __syncthreads();
    const float wn = (float)hasn[s];
    const float wp = (prevb[s] >= 0) ? 1.0f : 0.0f;
    for (int j = 0; j < 9; j++) {
        float acc = hp[j][t] / dgo[j] + bias[t];
        const float djj = di[j], nmj = nm[j];
        for (int u = 0; u < 9; u++)
            if (adj9(u, j)) acc += di[u] * djj * nm[u] * nmj * hp[u][t];
        if (j == 0) {
            acc += di[9]  * djj * wn * hp[9][t];
            acc += di[10] * djj * wp * hp[10][t];
        }
        out[((long)(s * 9 + j)) * F + t] = fmaxf(acc, 0.0f);
    }
}

// GCN layer-2 matmul: h2pre[N,32] = h1[N,64] @ W2[64,32]
__global__ __launch_bounds__(64)
void k_mm2(const float* __restrict__ h1, const float* __restrict__ W2,
           float* __restrict__ h2pre) {
    const int s = blockIdx.x;
    const int t = threadIdx.x;
    __shared__ float hf[9][64];
    __shared__ float wl[64][32];
    for (int idx = t; idx < 9 * 64; idx += 64) hf[idx >> 6][idx & 63] = h1[(long)s * 9 * 64 + idx];
    for (int idx = t; idx < 64 * 32; idx += 64) wl[idx >> 5][idx & 31] = W2[idx];
    __syncthreads();
    const int o = t & 31, jh = t >> 5;
    for (int j = jh; j < 9; j += 2) {
        float acc = 0.0f;
#pragma unroll
        for (int e = 0; e < 64; e++) acc += hf[j][e] * wl[e][o];
        h2pre[((long)(s * 9 + j)) * 32 + o] = acc;
    }
}

// samp_mean + gnn_pooled fused. grid B, block 32 (thread = gout dim)
__global__ void k_sampgnn(const float* __restrict__ h2, const int* __restrict__ validb,
                          const int* __restrict__ lesb, float* __restrict__ gnnp) {
    const int b = blockIdx.x;
    const int t = threadIdx.x;
    float acc = 0.0f, vcnt = 0.0f;
    for (int tt = 0; tt < 16; tt++) {
        const int s = b * 16 + tt;
        if (validb[s]) {
            const int lb = lesb[s];
            float cnt = 2.0f;
            float sm = h2[((long)(s * 9 + 0)) * 32 + t] + h2[((long)(s * 9 + 1)) * 32 + t];
#pragma unroll
            for (int k = 0; k < 7; k++) {
                if ((lb >> k) & 1) { cnt += 1.0f; sm += h2[((long)(s * 9 + 2 + k)) * 32 + t]; }
            }
            acc += sm / fmaxf(cnt, 1.0f);
            vcnt += 1.0f;
        }
    }
    gnnp[b * 32 + t] = acc / fmaxf(vcnt, 1.0f);
}

// diag head: logits, conf, ent
__global__ __launch_bounds__(256)
void k_diag(const float* __restrict__ pooled, const float* __restrict__ gnnp,
            const float* __restrict__ wd, const float* __restrict__ bd,
            float* __restrict__ o_dg, float* __restrict__ o_cf, float* __restrict__ o_en) {
    const int b = blockIdx.x;
    const int tid = threadIdx.x;
    float a[7];
#pragma unroll
    for (int c = 0; c < 7; c++) a[c] = 0.0f;
    for (int d = tid; d < 2080; d += 256) {
        const float v = (d < 2048) ? pooled[(long)b * 2048 + d] : gnnp[b * 32 + (d - 2048)];
#pragma unroll
        for (int c = 0; c < 7; c++) a[c] += v * wd[d * 7 + c];
    }
    __shared__ float red[4][7];
#pragma unroll
    for (int c = 0; c < 7; c++) {
        float v = a[c];
        for (int o = 32; o > 0; o >>= 1) v += __shfl_down(v, o, 64);
        if ((tid & 63) == 0) red[tid >> 6][c] = v;
    }
    __syncthreads();
    if (tid == 0) {
        float l[7];
        float m = -__builtin_inff();
#pragma unroll
        for (int c = 0; c < 7; c++) {
            l[c] = red[0][c] + red[1][c] + red[2][c] + red[3][c] + bd[c];
            o_dg[b * 7 + c] = l[c];
            m = fmaxf(m, l[c]);
        }
        float p[7], sum = 0.0f;
#pragma unroll
        for (int c = 0; c < 7; c++) { p[c] = expf(l[c] - m); sum += p[c]; }
        const float inv = 1.0f / sum;
        float conf = 0.0f, ent = 0.0f;
#pragma unroll
        for (int c = 0; c < 7; c++) {
            const float pr = p[c] * inv;
            conf = fmaxf(conf, pr);
            ent -= pr * logf(pr + 1e-8f);
        }
        o_cf[b] = conf;
        o_en[b] = ent * (1.0f / 1.9459101090932196f);  // / log(7)
    }
}

// ---------------------------------------------------------------------------
extern "C" void kernel_launch(void* const* d_in, const int* in_sizes, int n_in,
                              void* d_out, int out_size, void* d_ws, size_t ws_size,
                              hipStream_t stream) {
    const float* feat      = (const float*)d_in[0];
    const float* w_phase   = (const float*)d_in[1];
    const float* b_phase   = (const float*)d_in[2];
    const float* w_loc     = (const float*)d_in[3];
    const float* b_loc     = (const float*)d_in[4];
    const float* w_les     = (const float*)d_in[5];
    const float* b_les     = (const float*)d_in[6];
    const float* emb_phase = (const float*)d_in[7];
    const float* emb_loc   = (const float*)d_in[8];
    const float* les_emb_w = (const float*)d_in[9];
    const float* les_emb_b = (const float*)d_in[10];
    const float* qkv_w     = (const float*)d_in[11];
    const float* qkv_b     = (const float*)d_in[12];
    const float* o_w       = (const float*)d_in[13];
    const float* o_b       = (const float*)d_in[14];
    const float* ln1_g     = (const float*)d_in[15];
    const float* ln1_b     = (const float*)d_in[16];
    const float* ln2_g     = (const float*)d_in[17];
    const float* ln2_b     = (const float*)d_in[18];
    const float* ff1_w     = (const float*)d_in[19];
    const float* ff1_b     = (const float*)d_in[20];
    const float* ff2_w     = (const float*)d_in[21];
    const float* ff2_b     = (const float*)d_in[22];
    const float* w_score   = (const float*)d_in[23];
    const float* b_score   = (const float*)d_in[24];
    const float* gcn1_w    = (const float*)d_in[25];
    const float* gcn1_b    = (const float*)d_in[26];
    const float* gcn2_w    = (const float*)d_in[27];
    const float* gcn2_b    = (const float*)d_in[28];
    const float* w_diag    = (const float*)d_in[29];
    const float* b_diag    = (const float*)d_in[30];
    const int*   mask      = (const int*)d_in[31];

    float* out  = (float*)d_out;
    float* o_ph = out;           // (S,3)
    float* o_lc = out + 3072;    // (S,7)
    float* o_ls = out + 10240;   // (S,7)
    float* o_dg = out + 17408;   // (B,7)
    float* o_cf = out + 17856;   // (B,)
    float* o_en = out + 17920;   // (B,)

    float* w = (float*)d_ws;
    float* x      = w; w += (long)S_ * D_;        // 2M
    float* pbuf   = w; w += 4L * S_ * 2048;       // 8M (split-K partials)
    float* qkvb   = pbuf;                          // alias: lifetimes disjoint
    float* scores = w; w += S_;
    float* wts    = w; w += S_;
    float* pooled = w; w += (long)B_ * D_;
    float* h1pre  = w; w += (long)NN * HID_;
    float* h1     = w; w += (long)NN * HID_;
    float* h2pre  = w; w += (long)NN * GOUT_;
    float* h2     = w; w += (long)NN * GOUT_;
    float* degv   = w; w += NN;
    float* dinvv  = w; w += NN;
    float* gnnp   = w; w += B_ * GOUT_;
    int* ivs    = (int*)w;
    int* pid    = ivs;
    int* lid    = ivs + S_;
    int* lesb   = ivs + 2 * S_;
    int* validb = ivs + 3 * S_;
    int* nxtb   = ivs + 4 * S_;
    int* prevb  = ivs + 5 * S_;
    int* hasn   = ivs + 6 * S_;
    u16* ub   = (u16*)(ivs + 7 * S_);
    u16* featb = ub; ub += (long)S_ * D_;
    u16* xb    = ub; ub += (long)S_ * D_;
    u16* ctxb  = ub; ub += (long)S_ * D_;
    u16* ffbb  = ub; ub += (long)S_ * DFF_;
    u16* wbuf  = ub; ub += 3L * D_ * D_;          // largest weight tensor (per layer)

    k_heads<<<S_, 256, 0, stream>>>(feat, w_phase, b_phase, w_loc, b_loc, w_les, b_les,
                                    o_ph, o_lc, o_ls, pid, lid, lesb);
    k_f2b<<<2048, 256, 0, stream>>>(feat, featb, (long)S_ * D_);

    const float* xinf = feat;
    const u16*   xinb = featb;
    for (int l = 0; l < L_; l++) {
        // qkv projection (unsplit: 384 blocks)
        k_f2b<<<2048, 256, 0, stream>>>(qkv_w + (long)l * 3 * D_ * D_, wbuf, 3L * D_ * D_);
        gemm_bf<0><<<dim3(48, 8, 1), 256, 0, stream>>>(
            xinb, wbuf, qkv_b + (long)l * 3 * D_, qkvb, 3 * D_, D_, D_);
        k_attn<<<B_ * H_, 256, 0, stream>>>(qkvb, mask, ctxb);
        // o-projection (split-K=4: 512 blocks)
        k_f2b<<<2048, 256, 0, stream>>>(o_w + (long)l * D_ * D_, wbuf, (long)D_ * D_);
        gemm_bf<1><<<dim3(16, 8, 4), 256, 0, stream>>>(
            ctxb, wbuf, nullptr, pbuf, D_, D_, D_ / 4);
        k_ln4<<<S_, 256, 0, stream>>>(xinf, pbuf, o_b + (long)l * D_,
                                      ln1_g + (long)l * D_, ln1_b + (long)l * D_, x, xb);
        // ff1 (split-K=4)
        k_f2b<<<2048, 256, 0, stream>>>(ff1_w + (long)l * DFF_ * D_, wbuf, (long)DFF_ * D_);
        gemm_bf<1><<<dim3(16, 8, 4), 256, 0, stream>>>(
            xb, wbuf, nullptr, pbuf, DFF_, D_, D_ / 4);
        k_comb_relu<<<2048, 256, 0, stream>>>(pbuf, ff1_b + (long)l * DFF_, ffbb);
        // ff2 (split-K=4)
        k_f2b<<<2048, 256, 0, stream>>>(ff2_w + (long)l * D_ * DFF_, wbuf, (long)D_ * DFF_);
        gemm_bf<1><<<dim3(16, 8, 4), 256, 0, stream>>>(
            ffbb, wbuf, nullptr, pbuf, D_, DFF_, DFF_ / 4);
        k_ln4<<<S_, 256, 0, stream>>>(x, pbuf, ff2_b + (long)l * D_,
                                      ln2_g + (long)l * D_, ln2_b + (long)l * D_, x, xb);
        xinf = x;
        xinb = xb;
    }

    k_scores<<<S_, 256, 0, stream>>>(x, w_score, b_score, scores);
    k_softT<<<B_, 64, 0, stream>>>(scores, mask, wts, validb);
    k_pooled<<<dim3(8, B_), 256, 0, stream>>>(x, wts, pooled);
    k_nxt<<<1, 1024, 0, stream>>>(validb, nxtb, prevb, hasn);
    k_deg<<<S_, 64, 0, stream>>>(validb, lesb, hasn, prevb, degv, dinvv);
    k_mm1<<<S_, 64, 0, stream>>>(pid, lid, emb_phase, emb_loc, les_emb_w, les_emb_b, gcn1_w, h1pre);
    k_agg<64><<<S_, 64, 0, stream>>>(h1pre, degv, dinvv, validb, lesb, hasn, prevb, nxtb, gcn1_b, h1);
    k_mm2<<<S_, 64, 0, stream>>>(h1, gcn2_w, h2pre);
    k_agg<32><<<S_, 32, 0, stream>>>(h2pre, degv, dinvv, validb, lesb, hasn, prevb, nxtb, gcn2_b, h2);
    k_sampgnn<<<B_, 32, 0, stream>>>(h2, validb, lesb, gnnp);
    k_diag<<<B_, 256, 0, stream>>>(pooled, gnnp, w_diag, b_diag, o_dg, o_cf, o_en);
}

// Round 4
// 664.927 us; speedup vs baseline: 1.8150x; 1.0164x over previous
//
#include <hip/hip_runtime.h>
#include <hip/hip_bf16.h>
#include <math.h>

// Problem constants
#define B_    64
#define T_    16
#define S_    1024
#define D_    2048
#define DFF_  2048
#define H_    8
#define DH_   256
#define L_    2
#define E_    32
#define HID_  64
#define GOUT_ 32
#define NN    (S_ * 9)

typedef unsigned short u16;
typedef float f32x4 __attribute__((ext_vector_type(4)));
typedef __bf16 bf16x8 __attribute__((ext_vector_type(8)));

__device__ __forceinline__ u16 f2bf_rne(float x) {
    union { float f; unsigned u; } c; c.f = x;
    unsigned u = c.u;
    unsigned r = (u + 0x7fffu + ((u >> 16) & 1u)) >> 16;
    return (u16)r;
}

__device__ __forceinline__ void gll16(const u16* g, u16* l) {
    __builtin_amdgcn_global_load_lds(
        (const __attribute__((address_space(1))) unsigned int*)g,
        (__attribute__((address_space(3))) unsigned int*)l,
        16, 0, 0);
}

// ---------------------------------------------------------------------------
// fp32 -> bf16 bulk convert (memory-bound, vectorized 8/thread)
// ---------------------------------------------------------------------------
__global__ __launch_bounds__(256)
void k_f2b(const float* __restrict__ in, u16* __restrict__ out, long n) {
    const long stride = (long)gridDim.x * 256 * 8;
    for (long i = ((long)blockIdx.x * 256 + threadIdx.x) * 8; i < n; i += stride) {
        const float4 a = *(const float4*)(in + i);
        const float4 b = *(const float4*)(in + i + 4);
        *(ushort4*)(out + i)     = make_ushort4(f2bf_rne(a.x), f2bf_rne(a.y),
                                                f2bf_rne(a.z), f2bf_rne(a.w));
        *(ushort4*)(out + i + 4) = make_ushort4(f2bf_rne(b.x), f2bf_rne(b.y),
                                                f2bf_rne(b.z), f2bf_rne(b.w));
    }
}

// ---------------------------------------------------------------------------
// GEMM: C[M,N] = A[M,K] @ W[N,K]^T   (A, W bf16; fp32 accumulate)
// BM=BN=128, BK=32, 256 threads (4 waves), wave quadrant 64x64 (4x4 frags).
// global_load_lds width=16, double-buffered 2-phase.
// Always writes split-K partial per bz: C + bz*(S_*N).
// Grid is flattened+XCD-swizzled: requires (gx*gy*gz) % 8 == 0.
// ---------------------------------------------------------------------------
__global__ __launch_bounds__(256)
void gemm_bf(const u16* __restrict__ A, const u16* __restrict__ W,
             float* __restrict__ C, int N, int K, int KS) {
    __shared__ __align__(16) u16 As0[128 * 32];
    __shared__ __align__(16) u16 Bs0[128 * 32];
    __shared__ __align__(16) u16 As1[128 * 32];
    __shared__ __align__(16) u16 Bs1[128 * 32];
    const int tid  = threadIdx.x;
    const int lane = tid & 63;
    const int wv   = tid >> 6;
    const int wr   = wv >> 1, wc = wv & 1;

    // XCD-aware bijective swizzle (nwg % 8 == 0): XCD k owns a contiguous
    // chunk of tile-space -> weight-panel re-reads hit the local L2.
    const int gx = gridDim.x, gy = gridDim.y, gz = gridDim.z;
    int id = blockIdx.x + gx * (blockIdx.y + gy * blockIdx.z);
    const int nwg = gx * gy * gz;
    id = (id & 7) * (nwg >> 3) + (id >> 3);
    const int bx = id % gx;
    const int tq = id / gx;
    const int by = tq % gy;
    const int bz = tq / gy;

    const long m0 = (long)by * 128;
    const long n0 = (long)bx * 128;
    const int kbase = bz * KS;

    f32x4 acc[4][4];
#pragma unroll
    for (int i = 0; i < 4; i++)
#pragma unroll
        for (int j = 0; j < 4; j++)
#pragma unroll
            for (int r = 0; r < 4; r++) acc[i][j][r] = 0.0f;

    // staging: wave wv owns chunks c0,c1 (16 rows each) of both operands.
    const int c0 = wv * 2, c1 = wv * 2 + 1;
    const int rsub = lane >> 2;
    const int kcol = (lane & 3) * 8;
    const u16* ga0 = A + (m0 + c0 * 16 + rsub) * (long)K + kbase + kcol;
    const u16* ga1 = A + (m0 + c1 * 16 + rsub) * (long)K + kbase + kcol;
    const u16* gb0 = W + (n0 + c0 * 16 + rsub) * (long)K + kbase + kcol;
    const u16* gb1 = W + (n0 + c1 * 16 + rsub) * (long)K + kbase + kcol;

    auto STAGE = [&](u16* dstA, u16* dstB) {
        gll16(ga0, dstA + c0 * 512);
        gll16(ga1, dstA + c1 * 512);
        gll16(gb0, dstB + c0 * 512);
        gll16(gb1, dstB + c1 * 512);
        ga0 += 32; ga1 += 32; gb0 += 32; gb1 += 32;
    };

    STAGE(As0, Bs0);
    __syncthreads();   // drains vmcnt -> tile 0 resident

    u16 *rA = As0, *rB = Bs0, *sA = As1, *sB = Bs1;
    const int nt = KS / 32;
    const int rbase = lane & 15;
    const int koff  = (lane >> 4) * 8;

    for (int t = 0; t < nt; ++t) {
        if (t + 1 < nt) STAGE(sA, sB);   // in flight during compute
        bf16x8 af[4], bfr[4];
#pragma unroll
        for (int i = 0; i < 4; i++) {
            af[i]  = *(const bf16x8*)&rA[(wr * 64 + i * 16 + rbase) * 32 + koff];
            bfr[i] = *(const bf16x8*)&rB[(wc * 64 + i * 16 + rbase) * 32 + koff];
        }
#pragma unroll
        for (int i = 0; i < 4; i++)
#pragma unroll
            for (int j = 0; j < 4; j++)
                acc[i][j] = __builtin_amdgcn_mfma_f32_16x16x32_bf16(af[i], bfr[j], acc[i][j], 0, 0, 0);
        __syncthreads();                 // next tile ready; reads of rA/rB done
        u16* t1 = rA; rA = sA; sA = t1;
        u16* t2 = rB; rB = sB; sB = t2;
    }

    // Epilogue: write split-K partial. C/D: col = lane&15, row = (lane>>4)*4+reg.
    float* Cout = C + (long)bz * ((long)S_ * N);
    const int crow = (lane >> 4) * 4;
    const int ccol = lane & 15;
#pragma unroll
    for (int i = 0; i < 4; i++) {
#pragma unroll
        for (int j = 0; j < 4; j++) {
            const long mb = m0 + wr * 64 + i * 16 + crow;
            const long nb = n0 + wc * 64 + j * 16 + ccol;
#pragma unroll
            for (int r = 0; r < 4; r++)
                Cout[(mb + r) * (long)N + nb] = acc[i][j][r];
        }
    }
}

// ---------------------------------------------------------------------------
// Heads: phase/loc/les logits (exact fp32) + argmax ids + les_act bits
// ---------------------------------------------------------------------------
__global__ __launch_bounds__(256)
void k_heads(const float* __restrict__ feat,
             const float* __restrict__ w_ph, const float* __restrict__ b_ph,
             const float* __restrict__ w_lc, const float* __restrict__ b_lc,
             const float* __restrict__ w_ls, const float* __restrict__ b_ls,
             float* __restrict__ o_ph, float* __restrict__ o_lc, float* __restrict__ o_ls,
             int* __restrict__ pid, int* __restrict__ lid, int* __restrict__ lesb) {
    const long s = blockIdx.x;
    const int tid = threadIdx.x;
    float a[17];
#pragma unroll
    for (int k = 0; k < 17; k++) a[k] = 0.0f;
    for (int d = tid; d < D_; d += 256) {
        const float f = feat[s * D_ + d];
        a[0] += f * w_ph[d * 3 + 0];
        a[1] += f * w_ph[d * 3 + 1];
        a[2] += f * w_ph[d * 3 + 2];
#pragma unroll
        for (int c = 0; c < 7; c++) a[3 + c]  += f * w_lc[d * 7 + c];
#pragma unroll
        for (int c = 0; c < 7; c++) a[10 + c] += f * w_ls[d * 7 + c];
    }
    __shared__ float red[4][17];
#pragma unroll
    for (int k = 0; k < 17; k++) {
        float v = a[k];
        for (int o = 32; o > 0; o >>= 1) v += __shfl_down(v, o, 64);
        if ((tid & 63) == 0) red[tid >> 6][k] = v;
    }
    __syncthreads();
    if (tid == 0) {
        float l[17];
#pragma unroll
        for (int k = 0; k < 17; k++) l[k] = red[0][k] + red[1][k] + red[2][k] + red[3][k];
        l[0] += b_ph[0]; l[1] += b_ph[1]; l[2] += b_ph[2];
#pragma unroll
        for (int c = 0; c < 7; c++) { l[3 + c] += b_lc[c]; l[10 + c] += b_ls[c]; }
        o_ph[s * 3 + 0] = l[0]; o_ph[s * 3 + 1] = l[1]; o_ph[s * 3 + 2] = l[2];
#pragma unroll
        for (int c = 0; c < 7; c++) { o_lc[s * 7 + c] = l[3 + c]; o_ls[s * 7 + c] = l[10 + c]; }
        int bp = 0;
        for (int j = 1; j < 3; j++) if (l[j] > l[bp]) bp = j;
        pid[s] = bp;
        int bl = 0;
        for (int c = 1; c < 7; c++) if (l[3 + c] > l[3 + bl]) bl = c;
        lid[s] = bl;
        int bits = 0;
        for (int c = 0; c < 7; c++) if (l[10 + c] > 0.0f) bits |= (1 << c);
        lesb[s] = bits;
    }
}

// ---------------------------------------------------------------------------
// Attention fused with qkv split-K combine + bias.
// qkv[s][col] = part0[s*6144+col] + part1[...] + qkv_b[col]
// ---------------------------------------------------------------------------
__global__ __launch_bounds__(256)
void k_attn(const float* __restrict__ part, const float* __restrict__ qb,
            const int* __restrict__ mask, u16* __restrict__ ctxb) {
    const int bh = blockIdx.x;
    const int b = bh >> 3, h = bh & 7;
    __shared__ float qs[16][257], ks[16][257], vs[16][257];
    __shared__ float sc[16][16];
    const int tid = threadIdx.x;
    const long P6 = (long)S_ * 6144;
    for (int idx = tid; idx < 16 * 256; idx += 256) {
        const int t = idx >> 8, d = idx & 255;
        const long rb = ((long)(b * 16 + t)) * 6144 + h * 256 + d;
        const int cb = h * 256 + d;
        qs[t][d] = part[rb]        + part[rb + P6]        + qb[cb];
        ks[t][d] = part[rb + 2048] + part[rb + 2048 + P6] + qb[cb + 2048];
        vs[t][d] = part[rb + 4096] + part[rb + 4096 + P6] + qb[cb + 4096];
    }
    __syncthreads();
    {
        const int i = tid >> 4, j = tid & 15;
        float dot = 0.0f;
        for (int d = 0; d < 256; d++) dot += qs[i][d] * ks[j][d];
        float sv = dot * (1.0f / 16.0f);
        if (mask[b * 16 + j] == 0) sv = -1000000000.0f;
        sc[i][j] = sv;
    }
    __syncthreads();
    if (tid < 16) {
        const int i = tid;
        float m = sc[i][0];
#pragma unroll
        for (int j = 1; j < 16; j++) m = fmaxf(m, sc[i][j]);
        float p[16], sum = 0.0f;
#pragma unroll
        for (int j = 0; j < 16; j++) { p[j] = expf(sc[i][j] - m); sum += p[j]; }
        const float inv = 1.0f / sum;
#pragma unroll
        for (int j = 0; j < 16; j++) sc[i][j] = p[j] * inv;
    }
    __syncthreads();
    {
        const int i = tid >> 4, c = tid & 15;
        float av[16];
#pragma unroll
        for (int j = 0; j < 16; j++) av[j] = sc[i][j];
#pragma unroll
        for (int o = 0; o < 16; o++) {
            const int d = o * 16 + c;
            float accv = 0.0f;
#pragma unroll
            for (int j = 0; j < 16; j++) accv += av[j] * vs[j][d];
            ctxb[((long)(b * 16 + i)) * 2048 + h * 256 + d] = f2bf_rne(accv);
        }
    }
}

// ---------------------------------------------------------------------------
// LayerNorm fused with split-K combine:
// out = LN(xprev + sum_z part[z] + pb) * g + b  -> fp32 AND bf16 outputs
// ---------------------------------------------------------------------------
__global__ __launch_bounds__(256)
void k_ln4(const float* __restrict__ xprev, const float* __restrict__ part,
           const float* __restrict__ pb, const float* __restrict__ g,
           const float* __restrict__ bt, float* __restrict__ outf,
           u16* __restrict__ outb) {
    __shared__ float buf[D_];
    __shared__ float red[8];
    const long s = blockIdx.x;
    const int tid = threadIdx.x;
    const long base = s * D_;
    const long P = (long)S_ * D_;
    float lsum = 0.0f;
    for (int d = tid; d < D_; d += 256) {
        const long i = base + d;
        const float v = xprev[i] + pb[d]
                      + part[i] + part[i + P] + part[i + 2 * P] + part[i + 3 * P];
        buf[d] = v;
        lsum += v;
    }
    for (int o = 32; o > 0; o >>= 1) lsum += __shfl_down(lsum, o, 64);
    if ((tid & 63) == 0) red[tid >> 6] = lsum;
    __syncthreads();
    const float mean = (red[0] + red[1] + red[2] + red[3]) * (1.0f / D_);
    float lvar = 0.0f;
    for (int d = tid; d < D_; d += 256) { const float dv = buf[d] - mean; lvar += dv * dv; }
    for (int o = 32; o > 0; o >>= 1) lvar += __shfl_down(lvar, o, 64);
    if ((tid & 63) == 0) red[4 + (tid >> 6)] = lvar;
    __syncthreads();
    const float var = (red[4] + red[5] + red[6] + red[7]) * (1.0f / D_);
    const float rstd = 1.0f / sqrtf(var + 1e-5f);
    for (int d = tid; d < D_; d += 256) {
        const float v = (buf[d] - mean) * rstd * g[d] + bt[d];
        outf[base + d] = v;
        outb[base + d] = f2bf_rne(v);
    }
}

// split-K combine + bias + ReLU -> bf16 (for ff1 output)
__global__ __launch_bounds__(256)
void k_comb_relu(const float* __restrict__ part, const float* __restrict__ bias,
                 u16* __restrict__ outb) {
    const long i = ((long)blockIdx.x * 256 + threadIdx.x) * 4;  // over S_*DFF_
    const long P = (long)S_ * DFF_;
    const int n = (int)(i & (DFF_ - 1));
    float4 v  = *(const float4*)(part + i);
    const float4 v1 = *(const float4*)(part + i + P);
    const float4 v2 = *(const float4*)(part + i + 2 * P);
    const float4 v3 = *(const float4*)(part + i + 3 * P);
    const float4 bv = *(const float4*)(bias + n);
    v.x = fmaxf(v.x + v1.x + v2.x + v3.x + bv.x, 0.0f);
    v.y = fmaxf(v.y + v1.y + v2.y + v3.y + bv.y, 0.0f);
    v.z = fmaxf(v.z + v1.z + v2.z + v3.z + bv.z, 0.0f);
    v.w = fmaxf(v.w + v1.w + v2.w + v3.w + bv.w, 0.0f);
    *(ushort4*)(outb + i) = make_ushort4(f2bf_rne(v.x), f2bf_rne(v.y),
                                         f2bf_rne(v.z), f2bf_rne(v.w));
}

// ---------------------------------------------------------------------------
// Token scores: scores[s] = x[s] . w_score + b_score
// ---------------------------------------------------------------------------
__global__ __launch_bounds__(256)
void k_scores(const float* __restrict__ x, const float* __restrict__ w,
              const float* __restrict__ bsc, float* __restrict__ scores) {
    const long s = blockIdx.x;
    const int tid = threadIdx.x;
    __shared__ float red[4];
    float a = 0.0f;
    for (int d = tid; d < D_; d += 256) a += x[s * D_ + d] * w[d];
    for (int o = 32; o > 0; o >>= 1) a += __shfl_down(a, o, 64);
    if ((tid & 63) == 0) red[tid >> 6] = a;
    __syncthreads();
    if (tid == 0) scores[s] = red[0] + red[1] + red[2] + red[3] + bsc[0];
}

// Softmax over T per batch + valid flags
__global__ void k_softT(const float* __restrict__ scores, const int* __restrict__ mask,
                        float* __restrict__ wts, int* __restrict__ validb) {
    const int b = blockIdx.x;
    const int t = threadIdx.x;  // blockDim 64, lanes 0..15 active
    float sv = -__builtin_inff();
    int mk = 0;
    if (t < 16) {
        mk = mask[b * 16 + t];
        sv = mk ? scores[b * 16 + t] : -__builtin_inff();
    }
    float m = sv;
    for (int o = 8; o > 0; o >>= 1) m = fmaxf(m, __shfl_xor(m, o, 16));
    float p = (t < 16) ? expf(sv - m) : 0.0f;
    float sum = p;
    for (int o = 8; o > 0; o >>= 1) sum += __shfl_xor(sum, o, 16);
    if (t < 16) {
        const float wv = p / sum;
        wts[b * 16 + t] = wv;
        validb[b * 16 + t] = (mk && (wv >= 0.05f)) ? 1 : 0;
    }
}

// pooled[b][d] = sum_t wts[b,t] * x[b,t,d]     grid (8, 64)
__global__ __launch_bounds__(256)
void k_pooled(const float* __restrict__ x, const float* __restrict__ wts,
              float* __restrict__ pooled) {
    const int b = blockIdx.y;
    const int d = blockIdx.x * 256 + threadIdx.x;
    float acc = 0.0f;
#pragma unroll
    for (int t = 0; t < 16; t++)
        acc += wts[b * 16 + t] * x[((long)(b * 16 + t)) * D_ + d];
    pooled[(long)b * D_ + d] = acc;
}

// next-valid chain (reverse scan) + prev + has_nxt. Single block.
__global__ __launch_bounds__(1024)
void k_nxt(const int* __restrict__ validb, int* __restrict__ nxt,
           int* __restrict__ prevb, int* __restrict__ hasn) {
    __shared__ int v[S_], nx[S_], pv[S_];
    const int t = threadIdx.x;
    v[t] = validb[t];
    pv[t] = -1;
    __syncthreads();
    if (t == 0) {
        int carry = -1;
        for (int i = S_ - 1; i >= 0; i--) { nx[i] = carry; if (v[i]) carry = i; }
    }
    __syncthreads();
    const int h = (v[t] && nx[t] >= 0) ? 1 : 0;
    if (h) pv[nx[t]] = t;   // injective among valid
    __syncthreads();
    nxt[t] = nx[t];
    hasn[t] = h;
    prevb[t] = pv[t];
}

// 9-node intra-sample adjacency: 0-1, 1-{2..8}, all pairs within {2..8}
__device__ __forceinline__ bool adj9(int u, int v) {
    if (u == v) return false;
    const int mn = u < v ? u : v;
    const int mx = u < v ? v : u;
    return !(mn == 0 && mx >= 2);
}

__global__ __launch_bounds__(64)
void k_deg(const int* __restrict__ validb, const int* __restrict__ lesb,
           const int* __restrict__ hasn, const int* __restrict__ prevb,
           float* __restrict__ deg, float* __restrict__ dinv) {
    const int s = blockIdx.x;
    const int t = threadIdx.x;
    __shared__ float nm[9];
    if (t < 9) {
        const int vl = validb[s];
        nm[t] = (t < 2) ? (vl ? 1.0f : 0.0f)
                        : ((vl && ((lesb[s] >> (t - 2)) & 1)) ? 1.0f : 0.0f);
    }
    __syncthreads();
    if (t < 9) {
        float dg = 1.0f;
        for (int u = 0; u < 9; u++)
            if (adj9(u, t)) dg += nm[u] * nm[t];
        if (t == 0) {
            dg += (float)hasn[s];
            if (prevb[s] >= 0) dg += 1.0f;
        }
        deg[s * 9 + t] = dg;
        dinv[s * 9 + t] = 1.0f / sqrtf(dg);
    }
}

// GCN layer-1 matmul: h1pre[N,64] = nodes[N,32] @ W1[32,64]  (embeddings inline)
__global__ __launch_bounds__(64)
void k_mm1(const int* __restrict__ pid, const int* __restrict__ lid,
           const float* __restrict__ embp, const float* __restrict__ embl,
           const float* __restrict__ lesw, const float* __restrict__ lesbv,
           const float* __restrict__ W1, float* __restrict__ h1pre) {
    const int s = blockIdx.x;
    const int t = threadIdx.x;
    __shared__ float nf[9][32];
    __shared__ float wl[32][64];
    for (int idx = t; idx < 9 * 32; idx += 64) {
        const int j = idx >> 5, e = idx & 31;
        float v;
        if (j == 0)      v = embp[pid[s] * 32 + e];
        else if (j == 1) v = embl[lid[s] * 32 + e];
        else             v = lesw[(j - 2) * 32 + e] + lesbv[e];
        nf[j][e] = v;
    }
    for (int idx = t; idx < 32 * 64; idx += 64) wl[idx >> 6][idx & 63] = W1[idx];
    __syncthreads();
    for (int j = 0; j < 9; j++) {
        float acc = 0.0f;
#pragma unroll
        for (int e = 0; e < 32; e++) acc += nf[j][e] * wl[e][t];
        h1pre[((long)(s * 9 + j)) * 64 + t] = acc;
    }
}

// GCN aggregate: out = relu(agg + h/deg + bias). blockDim = F.
template<int F>
__global__ void k_agg(const float* __restrict__ hpre, const float* __restrict__ deg,
                      const float* __restrict__ dinv, const int* __restrict__ validb,
                      const int* __restrict__ lesb, const int* __restrict__ hasn,
                      const int* __restrict__ prevb, const int* __restrict__ nxt,
                      const float* __restrict__ bias, float* __restrict__ out) {
    const int s = blockIdx.x;
    const int t = threadIdx.x;
    __shared__ float hp[11][F];
    __shared__ float nm[9], di[11], dgo[9];
    for (int idx = t; idx < 11 * F; idx += F) {
        const int nl = idx / F, f = idx % F;
        float v = 0.0f;
        if (nl < 9) v = hpre[((long)(s * 9 + nl)) * F + f];
        else if (nl == 9)  { const int nx = nxt[s];  if (nx >= 0) v = hpre[((long)(nx * 9)) * F + f]; }
        else               { const int pb = prevb[s]; if (pb >= 0) v = hpre[((long)(pb * 9)) * F + f]; }
        hp[nl][f] = v;
    }
    if (t < 9) {
        const int vl = validb[s];
        nm[t] = (t < 2) ? (vl ? 1.0f : 0.0f)
                        : ((vl && ((lesb[s] >> (t - 2)) & 1)) ? 1.0f : 0.0f);
        di[t] = dinv[s * 9 + t];
        dgo[t] = deg[s * 9 + t];
    }
    if (t == 0) {
        const int nx = nxt[s];
        di[9]  = (nx >= 0) ? dinv[nx * 9] : 0.0f;
        const int pb = prevb[s];
        di[10] = (pb >= 0) ? dinv[pb * 9] : 0.0f;
    }
    __syncthreads();
    const float wn = (float)hasn[s];
    const float wp = (prevb[s] >= 0) ? 1.0f : 0.0f;
    for (int j = 0; j < 9; j++) {
        float acc = hp[j][t] / dgo[j] + bias[t];
        const float djj = di[j], nmj = nm[j];
        for (int u = 0; u < 9; u++)
            if (adj9(u, j)) acc += di[u] * djj * nm[u] * nmj * hp[u][t];
        if (j == 0) {
            acc += di[9]  * djj * wn * hp[9][t];
            acc += di[10] * djj * wp * hp[10][t];
        }
        out[((long)(s * 9 + j)) * F + t] = fmaxf(acc, 0.0f);
    }
}

// GCN layer-2 matmul: h2pre[N,32] = h1[N,64] @ W2[64,32]
__global__ __launch_bounds__(64)
void k_mm2(const float* __restrict__ h1, const float* __restrict__ W2,
           float* __restrict__ h2pre) {
    const int s = blockIdx.x;
    const int t = threadIdx.x;
    __shared__ float hf[9][64];
    __shared__ float wl[64][32];
    for (int idx = t; idx < 9 * 64; idx += 64) hf[idx >> 6][idx & 63] = h1[(long)s * 9 * 64 + idx];
    for (int idx = t; idx < 64 * 32; idx += 64) wl[idx >> 5][idx & 31] = W2[idx];
    __syncthreads();
    const int o = t & 31, jh = t >> 5;
    for (int j = jh; j < 9; j += 2) {
        float acc = 0.0f;
#pragma unroll
        for (int e = 0; e < 64; e++) acc += hf[j][e] * wl[e][o];
        h2pre[((long)(s * 9 + j)) * 32 + o] = acc;
    }
}

// samp_mean + gnn_pooled fused. grid B, block 32 (thread = gout dim)
__global__ void k_sampgnn(const float* __restrict__ h2, const int* __restrict__ validb,
                          const int* __restrict__ lesb, float* __restrict__ gnnp) {
    const int b = blockIdx.x;
    const int t = threadIdx.x;
    float acc = 0.0f, vcnt = 0.0f;
    for (int tt = 0; tt < 16; tt++) {
        const int s = b * 16 + tt;
        if (validb[s]) {
            const int lb = lesb[s];
            float cnt = 2.0f;
            float sm = h2[((long)(s * 9 + 0)) * 32 + t] + h2[((long)(s * 9 + 1)) * 32 + t];
#pragma unroll
            for (int k = 0; k < 7; k++) {
                if ((lb >> k) & 1) { cnt += 1.0f; sm += h2[((long)(s * 9 + 2 + k)) * 32 + t]; }
            }
            acc += sm / fmaxf(cnt, 1.0f);
            vcnt += 1.0f;
        }
    }
    gnnp[b * 32 + t] = acc / fmaxf(vcnt, 1.0f);
}

// diag head: logits, conf, ent
__global__ __launch_bounds__(256)
void k_diag(const float* __restrict__ pooled, const float* __restrict__ gnnp,
            const float* __restrict__ wd, const float* __restrict__ bd,
            float* __restrict__ o_dg, float* __restrict__ o_cf, float* __restrict__ o_en) {
    const int b = blockIdx.x;
    const int tid = threadIdx.x;
    float a[7];
#pragma unroll
    for (int c = 0; c < 7; c++) a[c] = 0.0f;
    for (int d = tid; d < 2080; d += 256) {
        const float v = (d < 2048) ? pooled[(long)b * 2048 + d] : gnnp[b * 32 + (d - 2048)];
#pragma unroll
        for (int c = 0; c < 7; c++) a[c] += v * wd[d * 7 + c];
    }
    __shared__ float red[4][7];
#pragma unroll
    for (int c = 0; c < 7; c++) {
        float v = a[c];
        for (int o = 32; o > 0; o >>= 1) v += __shfl_down(v, o, 64);
        if ((tid & 63) == 0) red[tid >> 6][c] = v;
    }
    __syncthreads();
    if (tid == 0) {
        float l[7];
        float m = -__builtin_inff();
#pragma unroll
        for (int c = 0; c < 7; c++) {
            l[c] = red[0][c] + red[1][c] + red[2][c] + red[3][c] + bd[c];
            o_dg[b * 7 + c] = l[c];
            m = fmaxf(m, l[c]);
        }
        float p[7], sum = 0.0f;
#pragma unroll
        for (int c = 0; c < 7; c++) { p[c] = expf(l[c] - m); sum += p[c]; }
        const float inv = 1.0f / sum;
        float conf = 0.0f, ent = 0.0f;
#pragma unroll
        for (int c = 0; c < 7; c++) {
            const float pr = p[c] * inv;
            conf = fmaxf(conf, pr);
            ent -= pr * logf(pr + 1e-8f);
        }
        o_cf[b] = conf;
        o_en[b] = ent * (1.0f / 1.9459101090932196f);  // / log(7)
    }
}

// ---------------------------------------------------------------------------
extern "C" void kernel_launch(void* const* d_in, const int* in_sizes, int n_in,
                              void* d_out, int out_size, void* d_ws, size_t ws_size,
                              hipStream_t stream) {
    const float* feat      = (const float*)d_in[0];
    const float* w_phase   = (const float*)d_in[1];
    const float* b_phase   = (const float*)d_in[2];
    const float* w_loc     = (const float*)d_in[3];
    const float* b_loc     = (const float*)d_in[4];
    const float* w_les     = (const float*)d_in[5];
    const float* b_les     = (const float*)d_in[6];
    const float* emb_phase = (const float*)d_in[7];
    const float* emb_loc   = (const float*)d_in[8];
    const float* les_emb_w = (const float*)d_in[9];
    const float* les_emb_b = (const float*)d_in[10];
    const float* qkv_w     = (const float*)d_in[11];
    const float* qkv_b     = (const float*)d_in[12];
    const float* o_w       = (const float*)d_in[13];
    const float* o_b       = (const float*)d_in[14];
    const float* ln1_g     = (const float*)d_in[15];
    const float* ln1_b     = (const float*)d_in[16];
    const float* ln2_g     = (const float*)d_in[17];
    const float* ln2_b     = (const float*)d_in[18];
    const float* ff1_w     = (const float*)d_in[19];
    const float* ff1_b     = (const float*)d_in[20];
    const float* ff2_w     = (const float*)d_in[21];
    const float* ff2_b     = (const float*)d_in[22];
    const float* w_score   = (const float*)d_in[23];
    const float* b_score   = (const float*)d_in[24];
    const float* gcn1_w    = (const float*)d_in[25];
    const float* gcn1_b    = (const float*)d_in[26];
    const float* gcn2_w    = (const float*)d_in[27];
    const float* gcn2_b    = (const float*)d_in[28];
    const float* w_diag    = (const float*)d_in[29];
    const float* b_diag    = (const float*)d_in[30];
    const int*   mask      = (const int*)d_in[31];

    float* out  = (float*)d_out;
    float* o_ph = out;           // (S,3)
    float* o_lc = out + 3072;    // (S,7)
    float* o_ls = out + 10240;   // (S,7)
    float* o_dg = out + 17408;   // (B,7)
    float* o_cf = out + 17856;   // (B,)
    float* o_en = out + 17920;   // (B,)

    float* w = (float*)d_ws;
    float* x      = w; w += (long)S_ * D_;        // 8 MB
    float* pbuf   = w; w += 2L * S_ * 6144;       // 48 MB: max(2*S*6144, 4*S*2048)
    float* scores = w; w += S_;
    float* wts    = w; w += S_;
    float* pooled = w; w += (long)B_ * D_;
    float* h1pre  = w; w += (long)NN * HID_;
    float* h1     = w; w += (long)NN * HID_;
    float* h2pre  = w; w += (long)NN * GOUT_;
    float* h2     = w; w += (long)NN * GOUT_;
    float* degv   = w; w += NN;
    float* dinvv  = w; w += NN;
    float* gnnp   = w; w += B_ * GOUT_;
    int* ivs    = (int*)w;
    int* pid    = ivs;
    int* lid    = ivs + S_;
    int* lesb   = ivs + 2 * S_;
    int* validb = ivs + 3 * S_;
    int* nxtb   = ivs + 4 * S_;
    int* prevb  = ivs + 5 * S_;
    int* hasn   = ivs + 6 * S_;
    u16* ub   = (u16*)(ivs + 7 * S_);
    u16* featb = ub; ub += (long)S_ * D_;
    u16* xb    = ub; ub += (long)S_ * D_;
    u16* ctxb  = ub; ub += (long)S_ * D_;
    u16* ffbb  = ub; ub += (long)S_ * DFF_;
    u16* wbuf  = ub; ub += 3L * D_ * D_;          // largest weight tensor (per layer)

    k_heads<<<S_, 256, 0, stream>>>(feat, w_phase, b_phase, w_loc, b_loc, w_les, b_les,
                                    o_ph, o_lc, o_ls, pid, lid, lesb);
    k_f2b<<<2048, 256, 0, stream>>>(feat, featb, (long)S_ * D_);

    const float* xinf = feat;
    const u16*   xinb = featb;
    for (int l = 0; l < L_; l++) {
        // qkv projection, split-K=2: 48*8*2 = 768 blocks (3/CU exact)
        k_f2b<<<2048, 256, 0, stream>>>(qkv_w + (long)l * 3 * D_ * D_, wbuf, 3L * D_ * D_);
        gemm_bf<<<dim3(48, 8, 2), 256, 0, stream>>>(xinb, wbuf, pbuf, 3 * D_, D_, D_ / 2);
        // attn fuses the 2-way partial combine + qkv bias
        k_attn<<<B_ * H_, 256, 0, stream>>>(pbuf, qkv_b + (long)l * 3 * D_, mask, ctxb);
        // o-projection, split-K=4: 512 blocks (2/CU exact)
        k_f2b<<<2048, 256, 0, stream>>>(o_w + (long)l * D_ * D_, wbuf, (long)D_ * D_);
        gemm_bf<<<dim3(16, 8, 4), 256, 0, stream>>>(ctxb, wbuf, pbuf, D_, D_, D_ / 4);
        k_ln4<<<S_, 256, 0, stream>>>(xinf, pbuf, o_b + (long)l * D_,
                                      ln1_g + (long)l * D_, ln1_b + (long)l * D_, x, xb);
        // ff1 (split-K=4)
        k_f2b<<<2048, 256, 0, stream>>>(ff1_w + (long)l * DFF_ * D_, wbuf, (long)DFF_ * D_);
        gemm_bf<<<dim3(16, 8, 4), 256, 0, stream>>>(xb, wbuf, pbuf, DFF_, D_, D_ / 4);
        k_comb_relu<<<2048, 256, 0, stream>>>(pbuf, ff1_b + (long)l * DFF_, ffbb);
        // ff2 (split-K=4)
        k_f2b<<<2048, 256, 0, stream>>>(ff2_w + (long)l * D_ * DFF_, wbuf, (long)D_ * DFF_);
        gemm_bf<<<dim3(16, 8, 4), 256, 0, stream>>>(ffbb, wbuf, pbuf, D_, DFF_, DFF_ / 4);
        k_ln4<<<S_, 256, 0, stream>>>(x, pbuf, ff2_b + (long)l * D_,
                                      ln2_g + (long)l * D_, ln2_b + (long)l * D_, x, xb);
        xinf = x;
        xinb = xb;
    }

    k_scores<<<S_, 256, 0, stream>>>(x, w_score, b_score, scores);
    k_softT<<<B_, 64, 0, stream>>>(scores, mask, wts, validb);
    k_pooled<<<dim3(8, B_), 256, 0, stream>>>(x, wts, pooled);
    k_nxt<<<1, 1024, 0, stream>>>(validb, nxtb, prevb, hasn);
    k_deg<<<S_, 64, 0, stream>>>(validb, lesb, hasn, prevb, degv, dinvv);
    k_mm1<<<S_, 64, 0, stream>>>(pid, lid, emb_phase, emb_loc, les_emb_w, les_emb_b, gcn1_w, h1pre);
    k_agg<64><<<S_, 64, 0, stream>>>(h1pre, degv, dinvv, validb, lesb, hasn, prevb, nxtb, gcn1_b, h1);
    k_mm2<<<S_, 64, 0, stream>>>(h1, gcn2_w, h2pre);
    k_agg<32><<<S_, 32, 0, stream>>>(h2pre, degv, dinvv, validb, lesb, hasn, prevb, nxtb, gcn2_b, h2);
    k_sampgnn<<<B_, 32, 0, stream>>>(h2, validb, lesb, gnnp);
    k_diag<<<B_, 256, 0, stream>>>(pooled, gnnp, w_diag, b_diag, o_dg, o_cf, o_en);
}